// Round 3
// baseline (2452.339 us; speedup 1.0000x reference)
//
#include <hip/hip_runtime.h>
#include <hip/hip_bf16.h>

typedef unsigned short u16;
typedef short bf16x8 __attribute__((ext_vector_type(8)));
typedef float f32x4 __attribute__((ext_vector_type(4)));

#define B_ 2
#define T_ 2048
#define E_ 1024
#define HQ_ 16
#define HKV_ 4
#define D_ 64
#define G_ 4

__device__ __forceinline__ u16 f2bf(float f) {
    union { float f; unsigned int i; } v; v.f = f;
    unsigned int x = v.i;
    return (u16)((x + 0x7fffu + ((x >> 16) & 1u)) >> 16);
}

__device__ __forceinline__ bf16x8 cvt8(const float* p) {
    float4 a = *(const float4*)p;
    float4 b = *(const float4*)(p + 4);
    bf16x8 r;
    r[0] = (short)f2bf(a.x); r[1] = (short)f2bf(a.y);
    r[2] = (short)f2bf(a.z); r[3] = (short)f2bf(a.w);
    r[4] = (short)f2bf(b.x); r[5] = (short)f2bf(b.y);
    r[6] = (short)f2bf(b.z); r[7] = (short)f2bf(b.w);
    return r;
}

// ---------------- QKV projection: C(4096x1536) = X(4096x1024) @ [Wq|Wk|Wv] + bias
// fp32 in, fp32 out; bf16 MFMA internally.
// A frag: A[m=lane&15][k=quad*8+j]  B frag: B[k=quad*8+j][n=lane&15]
// D frag: D[row=quad*4+r][col=lane&15]
__global__ __launch_bounds__(256) void qkv_gemm(
    const float* __restrict__ X,
    const float* __restrict__ Wq, const float* __restrict__ Wk, const float* __restrict__ Wv,
    const float* __restrict__ bq, const float* __restrict__ bk, const float* __restrict__ bv,
    float* __restrict__ qws, float* __restrict__ kws, float* __restrict__ vws)
{
    int lane = threadIdx.x & 63;
    int wave = threadIdx.x >> 6;
    int l16 = lane & 15;
    int quad = lane >> 4;
    int mtile = blockIdx.y;                 // 0..255
    int ntile = blockIdx.x * 4 + wave;      // 0..95
    int m = mtile * 16 + l16;
    int n = ntile * 16 + l16;

    const float* W; int ldw; const float* bias; int ncol;
    if (n < 1024)      { W = Wq; ldw = 1024; bias = bq; ncol = n; }
    else if (n < 1280) { W = Wk; ldw = 256;  bias = bk; ncol = n - 1024; }
    else               { W = Wv; ldw = 256;  bias = bv; ncol = n - 1280; }

    f32x4 acc = {0.f, 0.f, 0.f, 0.f};
    const float* arow = X + (size_t)m * 1024 + quad * 8;
    for (int kk = 0; kk < 1024; kk += 32) {
        bf16x8 a = cvt8(arow + kk);
        bf16x8 b;
        const float* wp = W + (size_t)(kk + quad * 8) * ldw + ncol;
        #pragma unroll
        for (int j = 0; j < 8; ++j) b[j] = (short)f2bf(wp[(size_t)j * ldw]);
        acc = __builtin_amdgcn_mfma_f32_16x16x32_bf16(a, b, acc, 0, 0, 0);
    }

    float bs = bias[ncol];
    #pragma unroll
    for (int r = 0; r < 4; ++r) {
        int rowm = mtile * 16 + quad * 4 + r;
        int bb = rowm >> 11, t = rowm & (T_ - 1);
        float h = acc[r] + bs;
        if (n < 1024) {
            int hq = n >> 6, dd = n & 63;
            qws[(((size_t)(bb * HQ_ + hq)) * T_ + t) * D_ + dd] = h;
        } else if (n < 1280) {
            int c2 = n - 1024; int kvh = c2 >> 6, dd = c2 & 63;
            kws[(((size_t)(bb * HKV_ + kvh)) * T_ + t) * D_ + dd] = h;
        } else {
            int c2 = n - 1280; int kvh = c2 >> 6, dd = c2 & 63;
            vws[(((size_t)(bb * HKV_ + kvh)) * T_ + t) * D_ + dd] = h;
        }
    }
}

// ---------------- RoPE in place (fp32), one thread per rotation pair
__global__ void rope_kernel(float* __restrict__ qws, float* __restrict__ kws) {
    const int QP = B_ * HQ_ * T_ * 32;   // 2,097,152
    const int KP = B_ * HKV_ * T_ * 32;  //   524,288
    int gid = blockIdx.x * blockDim.x + threadIdx.x;
    if (gid >= QP + KP) return;
    float* base; int row;
    if (gid < QP) { row = gid >> 5; base = qws + (size_t)row * 64; }
    else          { row = (gid - QP) >> 5; base = kws + (size_t)row * 64; }
    int ii = gid & 31;
    int t = row & (T_ - 1);
    double theta = pow(10000.0, -(double)ii / 32.0);
    double ang = (double)(t + 1) * theta;
    float c = (float)cos(ang), s = (float)sin(ang);
    float x1 = base[ii];
    float x2 = base[ii + 32];
    base[ii]      = x1 * c - x2 * s;
    base[ii + 32] = x2 * c + x1 * s;
}

// ---------------- attention: one block per (b,hq, 4 query rows). fp32 throughout.
// s2 layout: [j][4 rows] interleaved so softmax/PV read float4 per j.
__global__ __launch_bounds__(256) void attn_kernel(
    float* __restrict__ qws, const float* __restrict__ kws, const float* __restrict__ vws,
    float* __restrict__ att_out)
{
    __shared__ __align__(16) float s2[T_ * 4];     // 32 KB
    __shared__ __align__(16) float q_s[4 * 64];    // [r*64 + c]
    __shared__ __align__(16) float red[1024];
    __shared__ float s_inv[4];
    int tid = threadIdx.x;
    int lane = tid & 63, wave = tid >> 6;
    int i0 = blockIdx.x * 4;
    int imax = i0 + 3;
    int bh = blockIdx.y;
    int b = bh >> 4, hq = bh & 15;
    int kvh = hq >> 2, g = hq & 3;
    float* qbase = qws + ((size_t)bh * T_ + i0) * 64;
    const float* kb = kws + ((size_t)(b * HKV_ + kvh) * T_) * 64;
    const float* vb = vws + ((size_t)(b * HKV_ + kvh) * T_) * 64;
    q_s[tid] = qbase[tid];          // 4 rows x 64 = 256
    __syncthreads();

    // ---- scores: register-tiled 4 j's x 4 rows per thread per pass
    for (int jb = tid; jb <= imax; jb += 1024) {
        int js1 = jb + 256, js2 = jb + 512, js3 = jb + 768;
        const float4* kp0 = (const float4*)(kb + (size_t)jb * 64);
        const float4* kp1 = (const float4*)(kb + (size_t)(js1 <= imax ? js1 : imax) * 64);
        const float4* kp2 = (const float4*)(kb + (size_t)(js2 <= imax ? js2 : imax) * 64);
        const float4* kp3 = (const float4*)(kb + (size_t)(js3 <= imax ? js3 : imax) * 64);
        const float4* kp[4] = {kp0, kp1, kp2, kp3};
        float acc[4][4] = {};
        #pragma unroll
        for (int c = 0; c < 16; ++c) {
            float4 qv[4];
            #pragma unroll
            for (int r = 0; r < 4; ++r) qv[r] = *(const float4*)(q_s + r * 64 + c * 4);
            #pragma unroll
            for (int jj = 0; jj < 4; ++jj) {
                float4 u = kp[jj][c];
                #pragma unroll
                for (int r = 0; r < 4; ++r)
                    acc[jj][r] += qv[r].x * u.x + qv[r].y * u.y + qv[r].z * u.z + qv[r].w * u.w;
            }
        }
        int js[4] = {jb, js1, js2, js3};
        #pragma unroll
        for (int jj = 0; jj < 4; ++jj) {
            if (js[jj] <= imax) {
                float4 sv;
                sv.x = acc[jj][0] * 0.125f; sv.y = acc[jj][1] * 0.125f;
                sv.z = acc[jj][2] * 0.125f; sv.w = acc[jj][3] * 0.125f;
                *(float4*)(s2 + (size_t)js[jj] * 4) = sv;
            }
        }
    }
    __syncthreads();

    // ---- row max (causal-aware)
    float mr[4] = {-1e30f, -1e30f, -1e30f, -1e30f};
    for (int j = tid; j <= imax; j += 256) {
        float4 sv = *(const float4*)(s2 + (size_t)j * 4);
        if (j <= i0)     mr[0] = fmaxf(mr[0], sv.x);
        if (j <= i0 + 1) mr[1] = fmaxf(mr[1], sv.y);
        if (j <= i0 + 2) mr[2] = fmaxf(mr[2], sv.z);
        mr[3] = fmaxf(mr[3], sv.w);
    }
    #pragma unroll
    for (int off = 32; off; off >>= 1) {
        #pragma unroll
        for (int r = 0; r < 4; ++r) mr[r] = fmaxf(mr[r], __shfl_down(mr[r], off, 64));
    }
    if (lane == 0) {
        #pragma unroll
        for (int r = 0; r < 4; ++r) red[wave * 4 + r] = mr[r];
    }
    __syncthreads();
    #pragma unroll
    for (int r = 0; r < 4; ++r)
        mr[r] = fmaxf(fmaxf(red[r], red[4 + r]), fmaxf(red[8 + r], red[12 + r]));
    __syncthreads();   // protect red before reuse

    // ---- exp + sum (masked entries -> 0)
    float sr[4] = {0.f, 0.f, 0.f, 0.f};
    for (int j = tid; j <= imax; j += 256) {
        float4 sv = *(const float4*)(s2 + (size_t)j * 4);
        float p0 = (j <= i0)     ? __expf(sv.x - mr[0]) : 0.f;
        float p1 = (j <= i0 + 1) ? __expf(sv.y - mr[1]) : 0.f;
        float p2 = (j <= i0 + 2) ? __expf(sv.z - mr[2]) : 0.f;
        float p3 =                 __expf(sv.w - mr[3]);
        sr[0] += p0; sr[1] += p1; sr[2] += p2; sr[3] += p3;
        float4 pv; pv.x = p0; pv.y = p1; pv.z = p2; pv.w = p3;
        *(float4*)(s2 + (size_t)j * 4) = pv;
    }
    #pragma unroll
    for (int off = 32; off; off >>= 1) {
        #pragma unroll
        for (int r = 0; r < 4; ++r) sr[r] += __shfl_down(sr[r], off, 64);
    }
    if (lane == 0) {
        #pragma unroll
        for (int r = 0; r < 4; ++r) red[wave * 4 + r] = sr[r];
    }
    __syncthreads();
    float inv[4];
    #pragma unroll
    for (int r = 0; r < 4; ++r)
        inv[r] = 1.0f / (red[r] + red[4 + r] + red[8 + r] + red[12 + r]);
    if (tid < 4) s_inv[tid] = inv[tid];
    __syncthreads();   // protect red before PV reuse; publish s_inv

    // ---- write att_weights rows (fp32), zeros beyond causal frontier
    size_t abase = (((size_t)(b * G_ + g) * HKV_ + kvh) * T_ + i0) * T_;
    for (int j = tid; j < T_; j += 256) {
        float4 pv;
        if (j <= imax) pv = *(const float4*)(s2 + (size_t)j * 4);
        else { pv.x = 0.f; pv.y = 0.f; pv.z = 0.f; pv.w = 0.f; }
        att_out[abase + 0 * T_ + j] = pv.x * inv[0];
        att_out[abase + 1 * T_ + j] = pv.y * inv[1];
        att_out[abase + 2 * T_ + j] = pv.z * inv[2];
        att_out[abase + 3 * T_ + j] = pv.w * inv[3];
    }

    // ---- P @ V : 16 j-chunks x 16 d-groups (4 dims each)
    int dg = (tid & 15) * 4;
    int chunk = tid >> 4;          // 0..15
    float acc[4][4] = {};          // [row][dd]
    for (int j = chunk; j <= imax; j += 16) {
        float4 pv = *(const float4*)(s2 + (size_t)j * 4);
        float4 vv = *(const float4*)(vb + (size_t)j * 64 + dg);
        acc[0][0] += pv.x * vv.x; acc[0][1] += pv.x * vv.y; acc[0][2] += pv.x * vv.z; acc[0][3] += pv.x * vv.w;
        acc[1][0] += pv.y * vv.x; acc[1][1] += pv.y * vv.y; acc[1][2] += pv.y * vv.z; acc[1][3] += pv.y * vv.w;
        acc[2][0] += pv.z * vv.x; acc[2][1] += pv.z * vv.y; acc[2][2] += pv.z * vv.z; acc[2][3] += pv.z * vv.w;
        acc[3][0] += pv.w * vv.x; acc[3][1] += pv.w * vv.y; acc[3][2] += pv.w * vv.z; acc[3][3] += pv.w * vv.w;
    }
    // reduce the wave's 4 chunks (lane>>4): offsets 32, 16
    #pragma unroll
    for (int off = 32; off >= 16; off >>= 1) {
        #pragma unroll
        for (int r = 0; r < 4; ++r)
            #pragma unroll
            for (int dd = 0; dd < 4; ++dd)
                acc[r][dd] += __shfl_down(acc[r][dd], off, 64);
    }
    if (lane < 16) {
        #pragma unroll
        for (int r = 0; r < 4; ++r)
            #pragma unroll
            for (int dd = 0; dd < 4; ++dd)
                red[wave * 256 + lane * 16 + r * 4 + dd] = acc[r][dd];
    }
    __syncthreads();
    // final combine across 4 waves; write y in place over this block's q rows
    {
        int r = tid >> 6, d = tid & 63;
        int dgi = d >> 2, dd = d & 3;
        int idx = dgi * 16 + r * 4 + dd;
        float y = red[idx] + red[256 + idx] + red[512 + idx] + red[768 + idx];
        qbase[r * 64 + d] = y * s_inv[r];
    }
}

// ---------------- output projection: out(4096x1024) = Y @ Wo + bo  (fp32 I/O, bf16 MFMA)
// Y lives in qws with (b,hq,t,d) layout
__global__ __launch_bounds__(256) void out_gemm(
    const float* __restrict__ Y, const float* __restrict__ Wo, const float* __restrict__ bo,
    float* __restrict__ out)
{
    int lane = threadIdx.x & 63;
    int wave = threadIdx.x >> 6;
    int l16 = lane & 15;
    int quad = lane >> 4;
    int mtile = blockIdx.y;                 // 0..255
    int ntile = blockIdx.x * 4 + wave;      // 0..63
    int m = mtile * 16 + l16;
    int n = ntile * 16 + l16;
    int bb = m >> 11, t = m & (T_ - 1);

    f32x4 acc = {0.f, 0.f, 0.f, 0.f};
    for (int kk = 0; kk < 1024; kk += 32) {
        int ch = kk + quad * 8;            // 8-aligned, never straddles a 64-wide head
        int hq = ch >> 6, d0 = ch & 63;
        const float* ap = Y + (((size_t)(bb * HQ_ + hq) * T_ + t) * D_) + d0;
        bf16x8 a = cvt8(ap);
        bf16x8 b;
        const float* wp = Wo + (size_t)ch * 1024 + n;
        #pragma unroll
        for (int j = 0; j < 8; ++j) b[j] = (short)f2bf(wp[(size_t)j * 1024]);
        acc = __builtin_amdgcn_mfma_f32_16x16x32_bf16(a, b, acc, 0, 0, 0);
    }
    float bs = bo[n];
    #pragma unroll
    for (int r = 0; r < 4; ++r) {
        int rowm = mtile * 16 + quad * 4 + r;
        out[(size_t)rowm * 1024 + n] = acc[r] + bs;
    }
}

extern "C" void kernel_launch(void* const* d_in, const int* in_sizes, int n_in,
                              void* d_out, int out_size, void* d_ws, size_t ws_size,
                              hipStream_t stream) {
    const float* x  = (const float*)d_in[0];
    // d_in[1] = mask (int32) — causal triu, applied analytically
    const float* Wq = (const float*)d_in[2];
    const float* bq = (const float*)d_in[3];
    const float* Wk = (const float*)d_in[4];
    const float* bk = (const float*)d_in[5];
    const float* Wv = (const float*)d_in[6];
    const float* bv = (const float*)d_in[7];
    const float* Wo = (const float*)d_in[8];
    const float* bo = (const float*)d_in[9];

    float* out = (float*)d_out;
    float* qws = (float*)d_ws;          // (B,HQ,T,D)  4,194,304 floats; later holds y
    float* kws = qws + 4194304;         // (B,HKV,T,D) 1,048,576
    float* vws = kws + 1048576;         // (B,HKV,T,D) 1,048,576   -> ws total 24 MB
    float* att_out = out + 4194304;     // (B,G,HKV,T,T) fp32

    qkv_gemm<<<dim3(24, 256), 256, 0, stream>>>(x, Wq, Wk, Wv, bq, bk, bv, qws, kws, vws);
    rope_kernel<<<dim3((B_*HQ_*T_*32 + B_*HKV_*T_*32) / 256), 256, 0, stream>>>(qws, kws);
    attn_kernel<<<dim3(T_ / 4, B_ * HQ_), 256, 0, stream>>>(qws, kws, vws, att_out);
    out_gemm<<<dim3(16, 256), 256, 0, stream>>>(qws, Wo, bo, out);
}